// Round 10
// baseline (202.775 us; speedup 1.0000x reference)
//
#include <hip/hip_runtime.h>
#include <hip/hip_bf16.h>

typedef _Float16 half8 __attribute__((ext_vector_type(8)));
typedef unsigned short ushort8 __attribute__((ext_vector_type(8)));
typedef float floatx4 __attribute__((ext_vector_type(4)));

#define B_ 4
#define C_ 256
#define N_ 4096
#define NT 32            // 128-wide tiles per dim
#define TRI 528          // NT*(NT+1)/2 triangular tiles per batch

// workspace layout (bytes)
#define OFF_FN    ((size_t)0)                     // 4*4096*256 fp16 = 8 MB
#define OFF_PROB  ((size_t)(8u << 20))            // 16384 fp32 = 64 KB
#define OFF_PART  (OFF_PROB + 65536)              // 4096 fp32 block partials = 16 KB
#define OFF_CNT   (OFF_PART + 16384)              // 1 u32 completion counter
#define OFF_TOP   ((size_t)(16u << 20))           // 16384 rows x 32 jtiles x 8 u32 = 16 MB

__device__ __forceinline__ void gl_lds16(const void* g, void* l) {
    __builtin_amdgcn_global_load_lds(
        (const __attribute__((address_space(1))) void*)g,
        (__attribute__((address_space(3))) void*)l,
        16, 0, 0);
}

__device__ __forceinline__ void cas(uint32_t& a, uint32_t& b) {
    uint32_t hi = max(a, b); b = min(a, b); a = hi;
}

// Batcher odd-even mergesort, 8 elems, descending (19 CAS)
__device__ __forceinline__ void sort8(uint32_t v[8]) {
    cas(v[0],v[1]); cas(v[2],v[3]); cas(v[4],v[5]); cas(v[6],v[7]);
    cas(v[0],v[2]); cas(v[1],v[3]); cas(v[4],v[6]); cas(v[5],v[7]);
    cas(v[1],v[2]); cas(v[5],v[6]);
    cas(v[0],v[4]); cas(v[1],v[5]); cas(v[2],v[6]); cas(v[3],v[7]);
    cas(v[2],v[4]); cas(v[3],v[5]);
    cas(v[1],v[2]); cas(v[3],v[4]); cas(v[5],v[6]);
}

// r, n desc-sorted -> r = top-8 of union, desc-sorted (8 max + 12 CAS)
__device__ __forceinline__ void merge8(uint32_t r[8], const uint32_t n[8]) {
    uint32_t m[8];
#pragma unroll
    for (int i = 0; i < 8; ++i) m[i] = max(r[i], n[7 - i]);   // bitonic
    cas(m[0],m[4]); cas(m[1],m[5]); cas(m[2],m[6]); cas(m[3],m[7]);
    cas(m[0],m[2]); cas(m[1],m[3]); cas(m[4],m[6]); cas(m[5],m[7]);
    cas(m[0],m[1]); cas(m[2],m[3]); cas(m[4],m[5]); cas(m[6],m[7]);
#pragma unroll
    for (int i = 0; i < 8; ++i) r[i] = m[i];
}

// ---------------- Kernel 1: fused prep — reads feats once ----------------
#define TS 68
__global__ __launch_bounds__(256) void prep_kernel(const float* __restrict__ feats,
                                                   const float* __restrict__ logits,
                                                   _Float16* __restrict__ fn,
                                                   float* __restrict__ prob,
                                                   uint32_t* __restrict__ counter) {
    __shared__ __align__(16) float T[C_ * TS];
    __shared__ float S[256];
    __shared__ float I[64];

    const int t  = threadIdx.x;
    const int b  = blockIdx.x >> 6;
    const int i0 = (blockIdx.x & 63) * 64;
    const float* fb = feats + (size_t)b * C_ * N_;
    if (blockIdx.x == 0 && t == 0) *counter = 0u;   // reset last-block counter

#pragma unroll
    for (int k = 0; k < 16; ++k) {
        int ch = t + k * 256;
        int row = ch >> 4, col4 = ch & 15;
        float4 v = *(const float4*)(fb + (size_t)row * N_ + i0 + col4 * 4);
        *(float4*)&T[row * TS + col4 * 4] = v;
    }
    __syncthreads();
    {
        int i = t & 63, cq = t >> 6;
        float ss = 0.f;
#pragma unroll 8
        for (int j = 0; j < 64; ++j) { float v = T[(cq * 64 + j) * TS + i]; ss += v * v; }
        S[cq * 64 + i] = ss;
    }
    __syncthreads();
    if (t < 64) {
        float ss = S[t] + S[64 + t] + S[128 + t] + S[192 + t];
        I[t] = 1.f / fmaxf(sqrtf(ss), 1e-12f);
        float lg = logits[b * N_ + i0 + t];
        prob[b * N_ + i0 + t] = 1.f / (1.f + expf(-lg));
    }
    __syncthreads();
    {
        int i = t >> 2, chunk = t & 3;
        float s = I[i];
        _Float16* fr = fn + ((size_t)(b * N_ + i0 + i)) * C_ + chunk * 64;
#pragma unroll
        for (int v8 = 0; v8 < 8; ++v8) {
            half8 h;
#pragma unroll
            for (int e = 0; e < 8; ++e)
                h[e] = (_Float16)(T[(chunk * 64 + v8 * 8 + e) * TS + i] * s);
            *(half8*)(fr + v8 * 8) = h;
        }
    }
}

// ---------------- Kernel 2: triangular MFMA gram tile + dual-scan top-8 ----------------
// Tile kept COL-major as flipped u16 (Ch[col*CSH+row]); epilogue packs row-pairs via
// v_cvt_pkrtz (1 b32 write / 2 values). Contiguous col-scan always runs (on diag it
// IS the row scan, by symmetry); strided row-scan only off-diag.
#define CSH 136   // u16 col stride: 272B -> b128-aligned, window starts spread over banks
__global__ __launch_bounds__(256, 3) void gram_sel_kernel(const _Float16* __restrict__ fn,
                                                          uint32_t* __restrict__ top) {
    __shared__ __align__(16) char smem[128 * CSH * 2];   // 34816 B
    _Float16* As = (_Float16*)smem;                      // 16 KB (K-loop)
    _Float16* Bs = (_Float16*)(smem + 16384);            // 16 KB (K-loop)
    unsigned short* Ch = (unsigned short*)smem;          // col-major u16 tile (selection)
    uint32_t* Ms = (uint32_t*)smem;                      // pair-merge staging

    const int t    = threadIdx.x;
    const int lane = t & 63;
    const int w    = t >> 6;
    const int m16  = lane & 15;
    const int q    = lane >> 4;

    // triangular block index -> (b, it, jt) with it <= jt
    const int b = blockIdx.x / TRI;
    const int u = blockIdx.x - b * TRI;
    int it = (int)(32.5f - sqrtf(32.5f * 32.5f - 2.0f * (float)u));
    while (u >= (it + 1) * (65 - (it + 1)) / 2) ++it;
    while (u < it * (65 - it) / 2) --it;
    const int jt = it + (u - it * (65 - it) / 2);
    const bool diag = (it == jt);

    const int i0 = it * 128, j0 = jt * 128;
    const _Float16* fnb = fn + (size_t)b * N_ * C_;

    const int srowb = t >> 3;
    const int schunk = (t & 7) ^ (srowb & 7);
    const int sw = m16 & 7;

    floatx4 acc[2][8];
#pragma unroll
    for (int ri = 0; ri < 2; ++ri)
#pragma unroll
        for (int jj = 0; jj < 8; ++jj) acc[ri][jj] = floatx4{0.f, 0.f, 0.f, 0.f};

    for (int kc = 0; kc < 4; ++kc) {
#pragma unroll
        for (int r = 0; r < 4; ++r) {
            int row = r * 32 + srowb;
            const _Float16* gA = fnb + (size_t)(i0 + row) * C_ + kc * 64 + schunk * 8;
            const _Float16* gB = fnb + (size_t)(j0 + row) * C_ + kc * 64 + schunk * 8;
            gl_lds16(gA, (char*)As + r * 4096 + t * 16);
            gl_lds16(gB, (char*)Bs + r * 4096 + t * 16);
        }
        __syncthreads();
#pragma unroll
        for (int kk = 0; kk < 2; ++kk) {
            half8 a0 = *(const half8*)&As[(w * 32 + m16) * 64 + ((kk * 4 + q) ^ sw) * 8];
            half8 a1 = *(const half8*)&As[(w * 32 + 16 + m16) * 64 + ((kk * 4 + q) ^ sw) * 8];
#pragma unroll
            for (int jj = 0; jj < 8; ++jj) {
                half8 bf = *(const half8*)&Bs[(jj * 16 + m16) * 64 + ((kk * 4 + q) ^ sw) * 8];
                acc[0][jj] = __builtin_amdgcn_mfma_f32_16x16x32_f16(a0, bf, acc[0][jj], 0, 0, 0);
                acc[1][jj] = __builtin_amdgcn_mfma_f32_16x16x32_f16(a1, bf, acc[1][jj], 0, 0, 0);
            }
        }
        __syncthreads();
    }

    // ---- dump tile col-major as flipped u16, paired rows via cvt_pkrtz ----
    // C/D layout: col = jj*16+m16, rows = w*32+ri*16+q*4+{0..3}
#pragma unroll
    for (int jj = 0; jj < 8; ++jj)
#pragma unroll
        for (int ri = 0; ri < 2; ++ri) {
            const int col = jj * 16 + m16;
            const int row = w * 32 + ri * 16 + q * 4;
#pragma unroll
            for (int p = 0; p < 2; ++p) {
                auto pk2 = __builtin_amdgcn_cvt_pkrtz(acc[ri][jj][2 * p], acc[ri][jj][2 * p + 1]);
                uint32_t bits = __builtin_bit_cast(uint32_t, pk2);
                uint32_t s = (bits >> 15) & 0x00010001u;
                uint32_t fl = bits ^ (s * 0x7FFFu + 0x80008000u);   // per-half order-flip
                *(uint32_t*)&Ch[col * CSH + row + 2 * p] = fl;
            }
        }
    __syncthreads();

    // ---- contiguous col-scan (always): 2 threads/col, 64 rows each, b128 reads ----
    // packed idx = global ROW index. Off-diag: j-side partials; diag: == row result.
    uint32_t cpk[8], rpk[8];
    {
        const int ccol = t >> 1, cr0 = (t & 1) * 64;
        const unsigned short* cc = &Ch[ccol * CSH + cr0];
        const int ibase = i0 + cr0;
#pragma unroll
        for (int g = 0; g < 8; ++g) {
            ushort8 v = *(const ushort8*)(cc + g * 8);
            uint32_t cand[8];
#pragma unroll
            for (int e = 0; e < 8; ++e)
                cand[e] = ((uint32_t)v[e] << 16) | (uint32_t)(ibase + g * 8 + e);
            sort8(cand);
            if (g == 0) {
#pragma unroll
                for (int s = 0; s < 8; ++s) cpk[s] = cand[s];
            } else merge8(cpk, cand);
        }
    }
    // ---- strided row-scan (off-diag only): 2 threads/row, 64 cols each ----
    if (!diag) {
        const int rrow = t >> 1, ch0 = (t & 1) * 64;
        const unsigned short* cr = &Ch[ch0 * CSH + rrow];
        const int jbase = j0 + ch0;
#pragma unroll
        for (int g = 0; g < 8; ++g) {
            uint32_t cand[8];
#pragma unroll
            for (int e = 0; e < 8; ++e)
                cand[e] = ((uint32_t)cr[(g * 8 + e) * CSH] << 16) | (uint32_t)(jbase + g * 8 + e);
            sort8(cand);
            if (g == 0) {
#pragma unroll
                for (int s = 0; s < 8; ++s) rpk[s] = cand[s];
            } else merge8(rpk, cand);
        }
    }
    __syncthreads();   // done reading Ch; reuse as merge staging

    // ---- pair-merge across the 2 threads of each col/row, emit 8 u32 ----
    if (t & 1) {
#pragma unroll
        for (int s = 0; s < 8; ++s) Ms[(t >> 1) * 8 + s] = cpk[s];
        if (!diag) {
#pragma unroll
            for (int s = 0; s < 8; ++s) Ms[1024 + (t >> 1) * 8 + s] = rpk[s];
        }
    }
    __syncthreads();
    if (!(t & 1)) {
        uint32_t o[8];
#pragma unroll
        for (int s = 0; s < 8; ++s) o[s] = Ms[(t >> 1) * 8 + s];
        merge8(cpk, o);
        uint32_t* dst = top + (((size_t)b * N_ + j0 + (t >> 1)) * 32 + it) * 8;
        *(uint4*)dst       = make_uint4(cpk[0], cpk[1], cpk[2], cpk[3]);
        *(uint4*)(dst + 4) = make_uint4(cpk[4], cpk[5], cpk[6], cpk[7]);
        if (!diag) {
#pragma unroll
            for (int s = 0; s < 8; ++s) o[s] = Ms[1024 + (t >> 1) * 8 + s];
            merge8(rpk, o);
            uint32_t* dst2 = top + (((size_t)b * N_ + i0 + (t >> 1)) * 32 + jt) * 8;
            *(uint4*)dst2       = make_uint4(rpk[0], rpk[1], rpk[2], rpk[3]);
            *(uint4*)(dst2 + 4) = make_uint4(rpk[4], rpk[5], rpk[6], rpk[7]);
        }
    }
}

// ---------------- Kernel 3: merge partials + last-block final reduction ----------------
__global__ __launch_bounds__(256) void merge_kernel(const uint32_t* __restrict__ top,
                                                    const float* __restrict__ prob,
                                                    float* __restrict__ partials,
                                                    uint32_t* __restrict__ counter,
                                                    float* __restrict__ out) {
    __shared__ float red[4];
    __shared__ float red2[256];
    __shared__ int lastFlag;
    const int t = threadIdx.x;
    const int lane = t & 63;
    const int w = t >> 6;
    const int rg = blockIdx.x * 4 + w;             // 0..16383
    const int b = rg >> 12;

    uint4 v4 = ((const uint4*)(top + (size_t)rg * 256))[lane];
    uint32_t v[4] = {v4.x, v4.y, v4.z, v4.w};
    uint32_t m = max(max(v[0], v[1]), max(v[2], v[3]));

    const float* pb = prob + (b << 12);
    float p_r = prob[rg];
    float contrib = 0.f;
#pragma unroll
    for (int k = 0; k < 8; ++k) {
        uint32_t M = m;
#pragma unroll
        for (int off = 32; off; off >>= 1) M = max(M, (uint32_t)__shfl_xor((int)M, off));
        if (lane == k) contrib = fabsf(p_r - pb[M & 0xFFFu]);
#pragma unroll
        for (int s = 0; s < 4; ++s) v[s] = (v[s] == M) ? 0u : v[s];
        m = max(max(v[0], v[1]), max(v[2], v[3]));
    }
#pragma unroll
    for (int off = 32; off; off >>= 1) contrib += __shfl_xor(contrib, off);
    if (lane == 0) red[w] = contrib;
    __syncthreads();
    if (t == 0) {
        float p = red[0] + red[1] + red[2] + red[3];
        __hip_atomic_store(&partials[blockIdx.x], p, __ATOMIC_RELAXED, __HIP_MEMORY_SCOPE_AGENT);
        uint32_t old = __hip_atomic_fetch_add(counter, 1u, __ATOMIC_ACQ_REL, __HIP_MEMORY_SCOPE_AGENT);
        lastFlag = (old == 4095u);
    }
    __syncthreads();
    if (lastFlag) {
        float s = 0.f;
#pragma unroll
        for (int k = 0; k < 16; ++k)
            s += __hip_atomic_load(&partials[k * 256 + t], __ATOMIC_RELAXED, __HIP_MEMORY_SCOPE_AGENT);
        red2[t] = s;
        __syncthreads();
        for (int off = 128; off > 0; off >>= 1) {
            if (t < off) red2[t] += red2[t + off];
            __syncthreads();
        }
        if (t == 0) out[0] = red2[0] * (1.f / (B_ * N_ * 8.0f));
    }
}

extern "C" void kernel_launch(void* const* d_in, const int* in_sizes, int n_in,
                              void* d_out, int out_size, void* d_ws, size_t ws_size,
                              hipStream_t stream) {
    const float* feats  = (const float*)d_in[0];
    const float* logits = (const float*)d_in[1];
    float* out = (float*)d_out;
    char* ws = (char*)d_ws;
    _Float16* fn   = (_Float16*)(ws + OFF_FN);
    float* prob    = (float*)(ws + OFF_PROB);
    float* parts   = (float*)(ws + OFF_PART);
    uint32_t* cnt  = (uint32_t*)(ws + OFF_CNT);
    uint32_t* top  = (uint32_t*)(ws + OFF_TOP);

    prep_kernel<<<256, 256, 0, stream>>>(feats, logits, fn, prob, cnt);
    gram_sel_kernel<<<B_ * TRI, 256, 0, stream>>>(fn, top);
    merge_kernel<<<4096, 256, 0, stream>>>(top, prob, parts, cnt, out);
}

// Round 11
// 125.089 us; speedup vs baseline: 1.6211x; 1.6211x over previous
//
#include <hip/hip_runtime.h>
#include <hip/hip_bf16.h>

typedef _Float16 half8 __attribute__((ext_vector_type(8)));
typedef unsigned short ushort8 __attribute__((ext_vector_type(8)));
typedef float floatx4 __attribute__((ext_vector_type(4)));

#define B_ 4
#define C_ 256
#define N_ 4096
#define NT 32            // 128-wide tiles per dim
#define TRI 528          // NT*(NT+1)/2 triangular tiles per batch

// workspace layout (bytes)
#define OFF_FN    ((size_t)0)                     // 4*4096*256 fp16 = 8 MB
#define OFF_PROB  ((size_t)(8u << 20))            // 16384 fp32 = 64 KB
#define OFF_PART  (OFF_PROB + 65536)              // 4096 fp32 block partials = 16 KB
#define OFF_TOP   ((size_t)(16u << 20))           // 16384 rows x 32 jtiles x 8 u32 = 16 MB

__device__ __forceinline__ void gl_lds16(const void* g, void* l) {
    __builtin_amdgcn_global_load_lds(
        (const __attribute__((address_space(1))) void*)g,
        (__attribute__((address_space(3))) void*)l,
        16, 0, 0);
}

__device__ __forceinline__ void cas(uint32_t& a, uint32_t& b) {
    uint32_t hi = max(a, b); b = min(a, b); a = hi;
}

// Batcher odd-even mergesort, 8 elems, descending (19 CAS)
__device__ __forceinline__ void sort8(uint32_t v[8]) {
    cas(v[0],v[1]); cas(v[2],v[3]); cas(v[4],v[5]); cas(v[6],v[7]);
    cas(v[0],v[2]); cas(v[1],v[3]); cas(v[4],v[6]); cas(v[5],v[7]);
    cas(v[1],v[2]); cas(v[5],v[6]);
    cas(v[0],v[4]); cas(v[1],v[5]); cas(v[2],v[6]); cas(v[3],v[7]);
    cas(v[2],v[4]); cas(v[3],v[5]);
    cas(v[1],v[2]); cas(v[3],v[4]); cas(v[5],v[6]);
}

// r, n desc-sorted -> r = top-8 of union, desc-sorted (8 max + 12 CAS)
__device__ __forceinline__ void merge8(uint32_t r[8], const uint32_t n[8]) {
    uint32_t m[8];
#pragma unroll
    for (int i = 0; i < 8; ++i) m[i] = max(r[i], n[7 - i]);   // bitonic
    cas(m[0],m[4]); cas(m[1],m[5]); cas(m[2],m[6]); cas(m[3],m[7]);
    cas(m[0],m[2]); cas(m[1],m[3]); cas(m[4],m[6]); cas(m[5],m[7]);
    cas(m[0],m[1]); cas(m[2],m[3]); cas(m[4],m[5]); cas(m[6],m[7]);
#pragma unroll
    for (int i = 0; i < 8; ++i) r[i] = m[i];
}

// ---------------- Kernel 1: fused prep — reads feats once ----------------
#define TS 68
__global__ __launch_bounds__(256) void prep_kernel(const float* __restrict__ feats,
                                                   const float* __restrict__ logits,
                                                   _Float16* __restrict__ fn,
                                                   float* __restrict__ prob) {
    __shared__ __align__(16) float T[C_ * TS];
    __shared__ float S[256];
    __shared__ float I[64];

    const int t  = threadIdx.x;
    const int b  = blockIdx.x >> 6;
    const int i0 = (blockIdx.x & 63) * 64;
    const float* fb = feats + (size_t)b * C_ * N_;

#pragma unroll
    for (int k = 0; k < 16; ++k) {
        int ch = t + k * 256;
        int row = ch >> 4, col4 = ch & 15;
        float4 v = *(const float4*)(fb + (size_t)row * N_ + i0 + col4 * 4);
        *(float4*)&T[row * TS + col4 * 4] = v;
    }
    __syncthreads();
    {
        int i = t & 63, cq = t >> 6;
        float ss = 0.f;
#pragma unroll 8
        for (int j = 0; j < 64; ++j) { float v = T[(cq * 64 + j) * TS + i]; ss += v * v; }
        S[cq * 64 + i] = ss;
    }
    __syncthreads();
    if (t < 64) {
        float ss = S[t] + S[64 + t] + S[128 + t] + S[192 + t];
        I[t] = 1.f / fmaxf(sqrtf(ss), 1e-12f);
        float lg = logits[b * N_ + i0 + t];
        prob[b * N_ + i0 + t] = 1.f / (1.f + expf(-lg));
    }
    __syncthreads();
    {
        int i = t >> 2, chunk = t & 3;
        float s = I[i];
        _Float16* fr = fn + ((size_t)(b * N_ + i0 + i)) * C_ + chunk * 64;
#pragma unroll
        for (int v8 = 0; v8 < 8; ++v8) {
            half8 h;
#pragma unroll
            for (int e = 0; e < 8; ++e)
                h[e] = (_Float16)(T[(chunk * 64 + v8 * 8 + e) * TS + i] * s);
            *(half8*)(fr + v8 * 8) = h;
        }
    }
}

// ---------------- Kernel 2: triangular MFMA gram tile + dual-scan top-8 ----------------
// Tile kept COL-major as flipped u16 (Ch[col*CSH+row]); epilogue packs row-pairs via
// v_cvt_pkrtz (1 b32 write / 2 values). Contiguous col-scan always runs (on diag it
// IS the row scan, by symmetry); strided row-scan only off-diag.
#define CSH 136   // u16 col stride: 272B -> b128-aligned, window starts spread over banks
__global__ __launch_bounds__(256, 3) void gram_sel_kernel(const _Float16* __restrict__ fn,
                                                          uint32_t* __restrict__ top) {
    __shared__ __align__(16) char smem[128 * CSH * 2];   // 34816 B
    _Float16* As = (_Float16*)smem;                      // 16 KB (K-loop)
    _Float16* Bs = (_Float16*)(smem + 16384);            // 16 KB (K-loop)
    unsigned short* Ch = (unsigned short*)smem;          // col-major u16 tile (selection)
    uint32_t* Ms = (uint32_t*)smem;                      // pair-merge staging

    const int t    = threadIdx.x;
    const int lane = t & 63;
    const int w    = t >> 6;
    const int m16  = lane & 15;
    const int q    = lane >> 4;

    // triangular block index -> (b, it, jt) with it <= jt
    const int b = blockIdx.x / TRI;
    const int u = blockIdx.x - b * TRI;
    int it = (int)(32.5f - sqrtf(32.5f * 32.5f - 2.0f * (float)u));
    while (u >= (it + 1) * (65 - (it + 1)) / 2) ++it;
    while (u < it * (65 - it) / 2) --it;
    const int jt = it + (u - it * (65 - it) / 2);
    const bool diag = (it == jt);

    const int i0 = it * 128, j0 = jt * 128;
    const _Float16* fnb = fn + (size_t)b * N_ * C_;

    const int srowb = t >> 3;
    const int schunk = (t & 7) ^ (srowb & 7);
    const int sw = m16 & 7;

    floatx4 acc[2][8];
#pragma unroll
    for (int ri = 0; ri < 2; ++ri)
#pragma unroll
        for (int jj = 0; jj < 8; ++jj) acc[ri][jj] = floatx4{0.f, 0.f, 0.f, 0.f};

    for (int kc = 0; kc < 4; ++kc) {
#pragma unroll
        for (int r = 0; r < 4; ++r) {
            int row = r * 32 + srowb;
            const _Float16* gA = fnb + (size_t)(i0 + row) * C_ + kc * 64 + schunk * 8;
            const _Float16* gB = fnb + (size_t)(j0 + row) * C_ + kc * 64 + schunk * 8;
            gl_lds16(gA, (char*)As + r * 4096 + t * 16);
            gl_lds16(gB, (char*)Bs + r * 4096 + t * 16);
        }
        __syncthreads();
#pragma unroll
        for (int kk = 0; kk < 2; ++kk) {
            half8 a0 = *(const half8*)&As[(w * 32 + m16) * 64 + ((kk * 4 + q) ^ sw) * 8];
            half8 a1 = *(const half8*)&As[(w * 32 + 16 + m16) * 64 + ((kk * 4 + q) ^ sw) * 8];
#pragma unroll
            for (int jj = 0; jj < 8; ++jj) {
                half8 bf = *(const half8*)&Bs[(jj * 16 + m16) * 64 + ((kk * 4 + q) ^ sw) * 8];
                acc[0][jj] = __builtin_amdgcn_mfma_f32_16x16x32_f16(a0, bf, acc[0][jj], 0, 0, 0);
                acc[1][jj] = __builtin_amdgcn_mfma_f32_16x16x32_f16(a1, bf, acc[1][jj], 0, 0, 0);
            }
        }
        __syncthreads();
    }

    // ---- dump tile col-major as flipped u16, paired rows via cvt_pkrtz ----
    // C/D layout: col = jj*16+m16, rows = w*32+ri*16+q*4+{0..3}
#pragma unroll
    for (int jj = 0; jj < 8; ++jj)
#pragma unroll
        for (int ri = 0; ri < 2; ++ri) {
            const int col = jj * 16 + m16;
            const int row = w * 32 + ri * 16 + q * 4;
#pragma unroll
            for (int p = 0; p < 2; ++p) {
                auto pk2 = __builtin_amdgcn_cvt_pkrtz(acc[ri][jj][2 * p], acc[ri][jj][2 * p + 1]);
                uint32_t bits = __builtin_bit_cast(uint32_t, pk2);
                uint32_t s = (bits >> 15) & 0x00010001u;
                uint32_t fl = bits ^ (s * 0x7FFFu + 0x80008000u);   // per-half order-flip
                *(uint32_t*)&Ch[col * CSH + row + 2 * p] = fl;
            }
        }
    __syncthreads();

    // ---- contiguous col-scan (always): 2 threads/col, 64 rows each, b128 reads ----
    // packed idx = global ROW index. Off-diag: j-side partials; diag: == row result.
    uint32_t cpk[8], rpk[8];
    {
        const int ccol = t >> 1, cr0 = (t & 1) * 64;
        const unsigned short* cc = &Ch[ccol * CSH + cr0];
        const int ibase = i0 + cr0;
#pragma unroll
        for (int g = 0; g < 8; ++g) {
            ushort8 v = *(const ushort8*)(cc + g * 8);
            uint32_t cand[8];
#pragma unroll
            for (int e = 0; e < 8; ++e)
                cand[e] = ((uint32_t)v[e] << 16) | (uint32_t)(ibase + g * 8 + e);
            sort8(cand);
            if (g == 0) {
#pragma unroll
                for (int s = 0; s < 8; ++s) cpk[s] = cand[s];
            } else merge8(cpk, cand);
        }
    }
    // ---- strided row-scan (off-diag only): 2 threads/row, 64 cols each ----
    if (!diag) {
        const int rrow = t >> 1, ch0 = (t & 1) * 64;
        const unsigned short* cr = &Ch[ch0 * CSH + rrow];
        const int jbase = j0 + ch0;
#pragma unroll
        for (int g = 0; g < 8; ++g) {
            uint32_t cand[8];
#pragma unroll
            for (int e = 0; e < 8; ++e)
                cand[e] = ((uint32_t)cr[(g * 8 + e) * CSH] << 16) | (uint32_t)(jbase + g * 8 + e);
            sort8(cand);
            if (g == 0) {
#pragma unroll
                for (int s = 0; s < 8; ++s) rpk[s] = cand[s];
            } else merge8(rpk, cand);
        }
    }
    __syncthreads();   // done reading Ch; reuse as merge staging

    // ---- pair-merge across the 2 threads of each col/row, emit 8 u32 ----
    if (t & 1) {
#pragma unroll
        for (int s = 0; s < 8; ++s) Ms[(t >> 1) * 8 + s] = cpk[s];
        if (!diag) {
#pragma unroll
            for (int s = 0; s < 8; ++s) Ms[1024 + (t >> 1) * 8 + s] = rpk[s];
        }
    }
    __syncthreads();
    if (!(t & 1)) {
        uint32_t o[8];
#pragma unroll
        for (int s = 0; s < 8; ++s) o[s] = Ms[(t >> 1) * 8 + s];
        merge8(cpk, o);
        uint32_t* dst = top + (((size_t)b * N_ + j0 + (t >> 1)) * 32 + it) * 8;
        *(uint4*)dst       = make_uint4(cpk[0], cpk[1], cpk[2], cpk[3]);
        *(uint4*)(dst + 4) = make_uint4(cpk[4], cpk[5], cpk[6], cpk[7]);
        if (!diag) {
#pragma unroll
            for (int s = 0; s < 8; ++s) o[s] = Ms[1024 + (t >> 1) * 8 + s];
            merge8(rpk, o);
            uint32_t* dst2 = top + (((size_t)b * N_ + i0 + (t >> 1)) * 32 + jt) * 8;
            *(uint4*)dst2       = make_uint4(rpk[0], rpk[1], rpk[2], rpk[3]);
            *(uint4*)(dst2 + 4) = make_uint4(rpk[4], rpk[5], rpk[6], rpk[7]);
        }
    }
}

// ---------------- Kernel 3: merge 32 partials/row, gather prob, partial loss ----------------
// NOTE: plain stores + separate final reduce. Do NOT use acq_rel agent atomics here:
// round 10 showed they emit per-block L2 writeback/invalidate -> 90 µs (10x regression).
__global__ __launch_bounds__(256) void merge_kernel(const uint32_t* __restrict__ top,
                                                    const float* __restrict__ prob,
                                                    float* __restrict__ partials) {
    __shared__ float red[4];
    const int t = threadIdx.x;
    const int lane = t & 63;
    const int w = t >> 6;
    const int rg = blockIdx.x * 4 + w;             // 0..16383
    const int b = rg >> 12;

    uint4 v4 = ((const uint4*)(top + (size_t)rg * 256))[lane];
    uint32_t v[4] = {v4.x, v4.y, v4.z, v4.w};
    uint32_t m = max(max(v[0], v[1]), max(v[2], v[3]));

    const float* pb = prob + (b << 12);
    float p_r = prob[rg];
    float contrib = 0.f;
#pragma unroll
    for (int k = 0; k < 8; ++k) {
        uint32_t M = m;
#pragma unroll
        for (int off = 32; off; off >>= 1) M = max(M, (uint32_t)__shfl_xor((int)M, off));
        if (lane == k) contrib = fabsf(p_r - pb[M & 0xFFFu]);
#pragma unroll
        for (int s = 0; s < 4; ++s) v[s] = (v[s] == M) ? 0u : v[s];
        m = max(max(v[0], v[1]), max(v[2], v[3]));
    }
#pragma unroll
    for (int off = 32; off; off >>= 1) contrib += __shfl_xor(contrib, off);
    if (lane == 0) red[w] = contrib;
    __syncthreads();
    if (t == 0) partials[blockIdx.x] = red[0] + red[1] + red[2] + red[3];
}

// ---------------- Kernel 4: final reduce (4096 partials) ----------------
__global__ __launch_bounds__(256) void final_kernel(const float* __restrict__ partials,
                                                    float* __restrict__ out) {
    __shared__ float red[256];
    int t = threadIdx.x;
    float s = 0.f;
#pragma unroll
    for (int k = 0; k < 16; ++k) s += partials[k * 256 + t];
    red[t] = s;
    __syncthreads();
    for (int off = 128; off > 0; off >>= 1) {
        if (t < off) red[t] += red[t + off];
        __syncthreads();
    }
    if (t == 0) out[0] = red[0] * (1.f / (B_ * N_ * 8.0f));
}

extern "C" void kernel_launch(void* const* d_in, const int* in_sizes, int n_in,
                              void* d_out, int out_size, void* d_ws, size_t ws_size,
                              hipStream_t stream) {
    const float* feats  = (const float*)d_in[0];
    const float* logits = (const float*)d_in[1];
    float* out = (float*)d_out;
    char* ws = (char*)d_ws;
    _Float16* fn   = (_Float16*)(ws + OFF_FN);
    float* prob    = (float*)(ws + OFF_PROB);
    float* parts   = (float*)(ws + OFF_PART);
    uint32_t* top  = (uint32_t*)(ws + OFF_TOP);

    prep_kernel<<<256, 256, 0, stream>>>(feats, logits, fn, prob);
    gram_sel_kernel<<<B_ * TRI, 256, 0, stream>>>(fn, top);
    merge_kernel<<<4096, 256, 0, stream>>>(top, prob, parts);
    final_kernel<<<1, 256, 0, stream>>>(parts, out);
}